// Round 9
// baseline (879.931 us; speedup 1.0000x reference)
//
#include <hip/hip_runtime.h>

typedef unsigned int uint;

constexpr int NN   = 50000;
constexpr int EE   = 800000;
constexpr int FIN  = 64;
constexpr int EDIM = 16;
constexpr int HDIM = 128;
constexpr int GG   = 256;
constexpr float BN_EPS_C = 1e-5f;
constexpr int NB   = (NN + 255) / 256;
constexpr int NB1  = (NN + 1 + 255) / 256;

// ===========================================================================
// CSR build
// ===========================================================================
__global__ __launch_bounds__(256) void deg_kernel(
    const int* __restrict__ ei, uint* __restrict__ deg)
{
    const int e = blockIdx.x * 256 + threadIdx.x;
    if (e < EE) atomicAdd(&deg[ei[EE + e]], 1u);
}

__global__ __launch_bounds__(256) void scanA_kernel(
    const uint* __restrict__ deg, uint* __restrict__ bsum)
{
    const int i = blockIdx.x * 256 + threadIdx.x;
    uint v = (i < NN) ? deg[i] : 0u;
#pragma unroll
    for (int o = 32; o > 0; o >>= 1) v += __shfl_xor(v, o, 64);
    __shared__ uint ws[4];
    const int lane = threadIdx.x & 63, wid = threadIdx.x >> 6;
    if (lane == 0) ws[wid] = v;
    __syncthreads();
    if (threadIdx.x == 0) bsum[blockIdx.x] = ws[0] + ws[1] + ws[2] + ws[3];
}

__global__ __launch_bounds__(256) void scanB_kernel(uint* __restrict__ bsum)
{
    const int t = threadIdx.x;
    const int lane = t & 63, wid = t >> 6;
    const uint orig = (t < NB) ? bsum[t] : 0u;
    uint v = orig;
#pragma unroll
    for (int o = 1; o < 64; o <<= 1) {
        uint u = __shfl_up(v, o, 64);
        if (lane >= o) v += u;
    }
    __shared__ uint ws[4];
    if (lane == 63) ws[wid] = v;
    __syncthreads();
    uint add = 0;
    for (int w = 0; w < wid; ++w) add += ws[w];
    v += add;
    if (t < NB) bsum[t] = v - orig;
}

__global__ __launch_bounds__(256) void scanC_kernel(
    const uint* __restrict__ deg, const uint* __restrict__ bbase,
    uint* __restrict__ off, uint* __restrict__ cursor)
{
    const int i = blockIdx.x * 256 + threadIdx.x;
    const int lane = threadIdx.x & 63, wid = threadIdx.x >> 6;
    const uint orig = (i < NN) ? deg[i] : 0u;
    uint v = orig;
#pragma unroll
    for (int o = 1; o < 64; o <<= 1) {
        uint u = __shfl_up(v, o, 64);
        if (lane >= o) v += u;
    }
    __shared__ uint ws[4];
    if (lane == 63) ws[wid] = v;
    __syncthreads();
    uint add = 0;
    for (int w = 0; w < wid; ++w) add += ws[w];
    v += add;
    const uint excl = v - orig + bbase[blockIdx.x];
    if (i < NN) { off[i] = excl; cursor[i] = excl; }
    if (i == NN) off[NN] = EE;
}

template <bool PERM>
__global__ __launch_bounds__(256) void scatter_kernel(
    const int* __restrict__ ei, const float* __restrict__ ea,
    uint* __restrict__ cursor, uint* __restrict__ srcs,
    uint* __restrict__ eidx, float* __restrict__ ea_perm)
{
    const int e = blockIdx.x * 256 + threadIdx.x;
    if (e < EE) {
        const int d = ei[EE + e];
        const uint pos = atomicAdd(&cursor[d], 1u);
        srcs[pos] = (uint)ei[e];
        if (PERM) {
            const float4* s = (const float4*)(ea + (size_t)e * EDIM);
            float4* dst = (float4*)(ea_perm + (size_t)pos * EDIM);
            dst[0] = s[0]; dst[1] = s[1]; dst[2] = s[2]; dst[3] = s[3];
        } else {
            eidx[pos] = (uint)e;
        }
    }
}

// ===========================================================================
// Edge gather: ONE NODE PER WAVE64. Lane owns F = CIN/64 features.
// CSR position p is wave-uniform -> srcs[p] and the ea row scalarize to
// s_load (SMEM pipe); the only vector load per edge is one coalesced X row.
// Per-lane weights = EDIM*F floats (32/16 VGPR) -> register-resident.
// Unrolled x2, straight-line bodies (R6 pattern).
// ===========================================================================
template <int CIN, bool PERM>
__global__ __launch_bounds__(256) void gather_kernel(
    const float* __restrict__ X, const float* __restrict__ ea,
    const uint* __restrict__ off, const uint* __restrict__ srcs,
    const uint* __restrict__ eidx, const float* __restrict__ ew,
    const float* __restrict__ eb, float* __restrict__ Hout)
{
    constexpr int F = CIN / 64;          // floats per lane (2 or 1)
    const int wv   = threadIdx.x >> 6;
    const int lane = threadIdx.x & 63;
    const int n    = blockIdx.x * 4 + wv;
    if (n >= NN) return;
    const int j = lane * F;

    float w[EDIM][F];
#pragma unroll
    for (int k = 0; k < EDIM; ++k)
#pragma unroll
        for (int f = 0; f < F; ++f) w[k][f] = ew[k * CIN + j + f];
    float ebv[F];
#pragma unroll
    for (int f = 0; f < F; ++f) ebv[f] = eb[j + f];

    const uint o0 = off[n], o1 = off[n + 1];
    float acc[F];
#pragma unroll
    for (int f = 0; f < F; ++f) acc[f] = 0.0f;

    uint p = o0;
    for (; p + 2 <= o1; p += 2) {
        // edge stream: uniform addresses -> scalar loads
        const uint sA = (uint)__builtin_amdgcn_readfirstlane(srcs[p]);
        const uint sB = (uint)__builtin_amdgcn_readfirstlane(srcs[p + 1]);
        const size_t rA = PERM ? (size_t)p : (size_t)eidx[p];
        const size_t rB = PERM ? (size_t)(p + 1) : (size_t)eidx[p + 1];
        const float* eA = ea + rA * EDIM;
        const float* eB = ea + rB * EDIM;
        float aA[EDIM], aB[EDIM];
#pragma unroll
        for (int k = 0; k < EDIM; ++k) aA[k] = eA[k];
#pragma unroll
        for (int k = 0; k < EDIM; ++k) aB[k] = eB[k];

        float xA[F], xB[F];
        if (F == 2) {
            const float2 vA = *(const float2*)&X[(size_t)sA * CIN + j];
            const float2 vB = *(const float2*)&X[(size_t)sB * CIN + j];
            xA[0] = vA.x; xA[F - 1] = vA.y;
            xB[0] = vB.x; xB[F - 1] = vB.y;
        } else {
            xA[0] = X[(size_t)sA * CIN + j];
            xB[0] = X[(size_t)sB * CIN + j];
        }

        float lA[F], lB[F];
#pragma unroll
        for (int f = 0; f < F; ++f) { lA[f] = ebv[f]; lB[f] = ebv[f]; }
#pragma unroll
        for (int k = 0; k < EDIM; ++k)
#pragma unroll
            for (int f = 0; f < F; ++f) {
                lA[f] = fmaf(aA[k], w[k][f], lA[f]);
                lB[f] = fmaf(aB[k], w[k][f], lB[f]);
            }
#pragma unroll
        for (int f = 0; f < F; ++f) {
            acc[f] += fmaxf(xA[f] + lA[f], 0.f) + fmaxf(xB[f] + lB[f], 0.f);
        }
    }
    if (p < o1) {
        const uint sA = (uint)__builtin_amdgcn_readfirstlane(srcs[p]);
        const size_t rA = PERM ? (size_t)p : (size_t)eidx[p];
        const float* eA = ea + rA * EDIM;
        float aA[EDIM];
#pragma unroll
        for (int k = 0; k < EDIM; ++k) aA[k] = eA[k];
        float xA[F];
        if (F == 2) {
            const float2 vA = *(const float2*)&X[(size_t)sA * CIN + j];
            xA[0] = vA.x; xA[F - 1] = vA.y;
        } else {
            xA[0] = X[(size_t)sA * CIN + j];
        }
        float lA[F];
#pragma unroll
        for (int f = 0; f < F; ++f) lA[f] = ebv[f];
#pragma unroll
        for (int k = 0; k < EDIM; ++k)
#pragma unroll
            for (int f = 0; f < F; ++f) lA[f] = fmaf(aA[k], w[k][f], lA[f]);
#pragma unroll
        for (int f = 0; f < F; ++f) acc[f] += fmaxf(xA[f] + lA[f], 0.f);
    }

    // self term + store (64 lanes x F floats = full row, coalesced)
    if (F == 2) {
        const float2 self = *(const float2*)&X[(size_t)n * CIN + j];
        float2 outv;
        outv.x = acc[0] + self.x;
        outv.y = acc[F - 1] + self.y;
        *(float2*)&Hout[(size_t)n * CIN + j] = outv;
    } else {
        Hout[(size_t)n * CIN + j] = acc[0] + X[(size_t)n * CIN + j];
    }
}

// ===========================================================================
// Fused MLP: Y = relu(H @ W1 + b1) @ W2 + b2 (+ fused BN stats)
// ===========================================================================
template <int K>
__global__ __launch_bounds__(256) void mlp_kernel(
    const float* __restrict__ H,
    const float* __restrict__ w1, const float* __restrict__ b1,
    const float* __restrict__ w2, const float* __restrict__ b2,
    float* __restrict__ Y, float* __restrict__ stats)
{
    __shared__ float Hs[64][K];
    __shared__ float Ts[64][HDIM];

    const int t   = threadIdx.x;
    const int nb0 = blockIdx.x * 64;

    {
        constexpr int V = 64 * K / 4 / 256;
        const float4* src = (const float4*)(H + (size_t)nb0 * K);
        float4* dst = (float4*)(&Hs[0][0]);
#pragma unroll
        for (int i = 0; i < V; ++i) {
            const int i4 = t + 256 * i;
            const int node = nb0 + (i4 * 4) / K;
            float4 v = make_float4(0.f, 0.f, 0.f, 0.f);
            if (node < NN) v = src[i4];
            dst[i4] = v;
        }
    }
    __syncthreads();

    const int tx = t & 31, ty = t >> 5;
    const int jc = tx * 4;
    const int nb = ty * 8;

    float acc[8][4];
#pragma unroll
    for (int i = 0; i < 8; ++i)
#pragma unroll
        for (int c = 0; c < 4; ++c) acc[i][c] = 0.0f;

    for (int k = 0; k < K; k += 2) {
        const float4 wa = *(const float4*)&w1[(k)     * HDIM + jc];
        const float4 wb = *(const float4*)&w1[(k + 1) * HDIM + jc];
#pragma unroll
        for (int i = 0; i < 8; ++i) {
            const float2 h2 = *(const float2*)&Hs[nb + i][k];
            acc[i][0] = fmaf(h2.x, wa.x, acc[i][0]);
            acc[i][1] = fmaf(h2.x, wa.y, acc[i][1]);
            acc[i][2] = fmaf(h2.x, wa.z, acc[i][2]);
            acc[i][3] = fmaf(h2.x, wa.w, acc[i][3]);
            acc[i][0] = fmaf(h2.y, wb.x, acc[i][0]);
            acc[i][1] = fmaf(h2.y, wb.y, acc[i][1]);
            acc[i][2] = fmaf(h2.y, wb.z, acc[i][2]);
            acc[i][3] = fmaf(h2.y, wb.w, acc[i][3]);
        }
    }
    {
        const float4 bb = *(const float4*)&b1[jc];
#pragma unroll
        for (int i = 0; i < 8; ++i) {
            float4 v;
            v.x = fmaxf(acc[i][0] + bb.x, 0.f);
            v.y = fmaxf(acc[i][1] + bb.y, 0.f);
            v.z = fmaxf(acc[i][2] + bb.z, 0.f);
            v.w = fmaxf(acc[i][3] + bb.w, 0.f);
            *(float4*)&Ts[nb + i][jc] = v;
        }
    }
    __syncthreads();

#pragma unroll
    for (int i = 0; i < 8; ++i)
#pragma unroll
        for (int c = 0; c < 4; ++c) acc[i][c] = 0.0f;

    for (int k = 0; k < HDIM; k += 2) {
        const float4 wa = *(const float4*)&w2[(k)     * HDIM + jc];
        const float4 wb = *(const float4*)&w2[(k + 1) * HDIM + jc];
#pragma unroll
        for (int i = 0; i < 8; ++i) {
            const float2 h2 = *(const float2*)&Ts[nb + i][k];
            acc[i][0] = fmaf(h2.x, wa.x, acc[i][0]);
            acc[i][1] = fmaf(h2.x, wa.y, acc[i][1]);
            acc[i][2] = fmaf(h2.x, wa.z, acc[i][2]);
            acc[i][3] = fmaf(h2.x, wa.w, acc[i][3]);
            acc[i][0] = fmaf(h2.y, wb.x, acc[i][0]);
            acc[i][1] = fmaf(h2.y, wb.y, acc[i][1]);
            acc[i][2] = fmaf(h2.y, wb.z, acc[i][2]);
            acc[i][3] = fmaf(h2.y, wb.w, acc[i][3]);
        }
    }

    float sp[4] = {0.f, 0.f, 0.f, 0.f};
    float qp[4] = {0.f, 0.f, 0.f, 0.f};
    {
        const float4 bb = *(const float4*)&b2[jc];
#pragma unroll
        for (int i = 0; i < 8; ++i) {
            const int node = nb0 + nb + i;
            if (node < NN) {
                float4 y;
                y.x = acc[i][0] + bb.x;
                y.y = acc[i][1] + bb.y;
                y.z = acc[i][2] + bb.z;
                y.w = acc[i][3] + bb.w;
                *(float4*)&Y[(size_t)node * HDIM + jc] = y;
                sp[0] += y.x; qp[0] = fmaf(y.x, y.x, qp[0]);
                sp[1] += y.y; qp[1] = fmaf(y.y, y.y, qp[1]);
                sp[2] += y.z; qp[2] = fmaf(y.z, y.z, qp[2]);
                sp[3] += y.w; qp[3] = fmaf(y.w, y.w, qp[3]);
            }
        }
    }
    __syncthreads();
    float* rs = &Ts[0][0];
    float* rq = &Ts[0][0] + 1024;
#pragma unroll
    for (int c = 0; c < 4; ++c) {
        rs[ty * HDIM + jc + c] = sp[c];
        rq[ty * HDIM + jc + c] = qp[c];
    }
    __syncthreads();
    if (t < HDIM) {
        float ss = 0.f, qq = 0.f;
#pragma unroll
        for (int r = 0; r < 8; ++r) {
            ss += rs[r * HDIM + t];
            qq += rq[r * HDIM + t];
        }
        unsafeAtomicAdd(&stats[t], ss);
        unsafeAtomicAdd(&stats[HDIM + t], qq);
    }
}

// ===========================================================================
// BN apply + relu
// ===========================================================================
__global__ __launch_bounds__(256) void bnrelu_kernel(
    const float* __restrict__ Y, const float* __restrict__ stats,
    const float* __restrict__ g, const float* __restrict__ b,
    float* __restrict__ Xo)
{
    constexpr int TOT4 = NN * (HDIM / 4);
    constexpr float inv_n = 1.0f / (float)NN;
    for (int i = blockIdx.x * 256 + threadIdx.x; i < TOT4; i += gridDim.x * 256) {
        const int j4 = i & (HDIM / 4 - 1);
        const float4 y  = ((const float4*)Y)[i];
        const float4 su = ((const float4*)stats)[j4];
        const float4 sq = ((const float4*)(stats + HDIM))[j4];
        const float4 gg = ((const float4*)g)[j4];
        const float4 bb = ((const float4*)b)[j4];
        float4 v;
        {
            float mu = su.x * inv_n, var = sq.x * inv_n - mu * mu;
            v.x = fmaxf((y.x - mu) * (gg.x * rsqrtf(fmaxf(var, 0.f) + BN_EPS_C)) + bb.x, 0.f);
        }
        {
            float mu = su.y * inv_n, var = sq.y * inv_n - mu * mu;
            v.y = fmaxf((y.y - mu) * (gg.y * rsqrtf(fmaxf(var, 0.f) + BN_EPS_C)) + bb.y, 0.f);
        }
        {
            float mu = su.z * inv_n, var = sq.z * inv_n - mu * mu;
            v.z = fmaxf((y.z - mu) * (gg.z * rsqrtf(fmaxf(var, 0.f) + BN_EPS_C)) + bb.z, 0.f);
        }
        {
            float mu = su.w * inv_n, var = sq.w * inv_n - mu * mu;
            v.w = fmaxf((y.w - mu) * (gg.w * rsqrtf(fmaxf(var, 0.f) + BN_EPS_C)) + bb.w, 0.f);
        }
        ((float4*)Xo)[i] = v;
    }
}

// ===========================================================================
// Layer-3 fused: BN+relu + per-graph mean pool + final linear.
// ===========================================================================
__global__ __launch_bounds__(128) void poolfinal_kernel(
    const float* __restrict__ Y, const float* __restrict__ stats,
    const float* __restrict__ g, const float* __restrict__ b,
    const int* __restrict__ batch, const float* __restrict__ lw,
    const float* __restrict__ lb, float* __restrict__ out)
{
    __shared__ float red[2];
    const int gid = blockIdx.x;
    const int j = threadIdx.x;

    auto lower_bound = [&](int key) {
        int lo = 0, hi = NN;
        while (lo < hi) { int m = (lo + hi) >> 1; if (batch[m] < key) lo = m + 1; else hi = m; }
        return lo;
    };
    const int s = lower_bound(gid);
    const int e = lower_bound(gid + 1);

    constexpr float inv_n = 1.0f / (float)NN;
    const float mu  = stats[j] * inv_n;
    const float var = stats[HDIM + j] * inv_n - mu * mu;
    const float sc  = g[j] * rsqrtf(fmaxf(var, 0.f) + BN_EPS_C);
    const float sh  = b[j];

    float acc = 0.0f;
    for (int n = s; n < e; ++n)
        acc += fmaxf((Y[(size_t)n * HDIM + j] - mu) * sc + sh, 0.0f);

    const float cnt = fmaxf((float)(e - s), 1.0f);
    float v = acc / cnt * lw[j];
    for (int o = 32; o > 0; o >>= 1) v += __shfl_down(v, o, 64);
    if ((j & 63) == 0) red[j >> 6] = v;
    __syncthreads();
    if (j == 0) out[gid] = red[0] + red[1] + lb[0];
}

// ===========================================================================
extern "C" void kernel_launch(void* const* d_in, const int* in_sizes, int n_in,
                              void* d_out, int out_size, void* d_ws, size_t ws_size,
                              hipStream_t stream)
{
    const float* x     = (const float*)d_in[0];
    const float* ea    = (const float*)d_in[1];
    const int*   ei    = (const int*)d_in[2];
    const int*   batch = (const int*)d_in[3];

    const float* ew[3]  = {(const float*)d_in[4],  (const float*)d_in[12], (const float*)d_in[20]};
    const float* ebv[3] = {(const float*)d_in[5],  (const float*)d_in[13], (const float*)d_in[21]};
    const float* w1[3]  = {(const float*)d_in[6],  (const float*)d_in[14], (const float*)d_in[22]};
    const float* b1[3]  = {(const float*)d_in[7],  (const float*)d_in[15], (const float*)d_in[23]};
    const float* w2[3]  = {(const float*)d_in[8],  (const float*)d_in[16], (const float*)d_in[24]};
    const float* b2[3]  = {(const float*)d_in[9],  (const float*)d_in[17], (const float*)d_in[25]};
    const float* bng[3] = {(const float*)d_in[10], (const float*)d_in[18], (const float*)d_in[26]};
    const float* bnb[3] = {(const float*)d_in[11], (const float*)d_in[19], (const float*)d_in[27]};
    const float* linw = (const float*)d_in[28];
    const float* linb = (const float*)d_in[29];

    // ---- workspace layout ----
    char* p = (char*)d_ws;
    float* bufA  = (float*)p;  p += (size_t)NN * HDIM * 4;
    float* bufB  = (float*)p;  p += (size_t)NN * HDIM * 4;
    float* stats = (float*)p;  p += 3 * 2 * HDIM * 4;
    uint* off    = (uint*)p;   p += ((NN + 4) & ~3) * 4;
    uint* degcur = (uint*)p;   p += (size_t)NN * 4;
    uint* bsum   = (uint*)p;   p += ((NB + 3) & ~3) * 4;
    uint* srcs   = (uint*)p;   p += (size_t)EE * 4;
    const size_t used_base = (size_t)(p - (char*)d_ws);
    const bool use_perm = ws_size >= used_base + (size_t)EE * EDIM * 4;
    float* ea_perm = (float*)p;
    uint*  eidx    = (uint*)p;

    hipMemsetAsync(degcur, 0, (size_t)NN * 4, stream);
    hipMemsetAsync(stats, 0, 3 * 2 * HDIM * 4, stream);
    deg_kernel<<<(EE + 255) / 256, 256, 0, stream>>>(ei, degcur);
    scanA_kernel<<<NB, 256, 0, stream>>>(degcur, bsum);
    scanB_kernel<<<1, 256, 0, stream>>>(bsum);
    scanC_kernel<<<NB1, 256, 0, stream>>>(degcur, bsum, off, degcur /*cursor*/);
    if (use_perm)
        scatter_kernel<true><<<(EE + 255) / 256, 256, 0, stream>>>(ei, ea, degcur, srcs, eidx, ea_perm);
    else
        scatter_kernel<false><<<(EE + 255) / 256, 256, 0, stream>>>(ei, ea, degcur, srcs, eidx, ea_perm);

    const int mlp_grid = (NN + 63) / 64;
    const int ggrid = (NN + 3) / 4;   // one node per wave, 4 waves per block

    if (use_perm) {
        gather_kernel<FIN, true><<<ggrid, 256, 0, stream>>>(x, ea_perm, off, srcs, eidx, ew[0], ebv[0], bufA);
        mlp_kernel<FIN><<<mlp_grid, 256, 0, stream>>>(bufA, w1[0], b1[0], w2[0], b2[0], bufB, stats);
        bnrelu_kernel<<<2048, 256, 0, stream>>>(bufB, stats, bng[0], bnb[0], bufA);

        gather_kernel<HDIM, true><<<ggrid, 256, 0, stream>>>(bufA, ea_perm, off, srcs, eidx, ew[1], ebv[1], bufB);
        mlp_kernel<HDIM><<<mlp_grid, 256, 0, stream>>>(bufB, w1[1], b1[1], w2[1], b2[1], bufB, stats + 256);
        bnrelu_kernel<<<2048, 256, 0, stream>>>(bufB, stats + 256, bng[1], bnb[1], bufA);

        gather_kernel<HDIM, true><<<ggrid, 256, 0, stream>>>(bufA, ea_perm, off, srcs, eidx, ew[2], ebv[2], bufB);
        mlp_kernel<HDIM><<<mlp_grid, 256, 0, stream>>>(bufB, w1[2], b1[2], w2[2], b2[2], bufB, stats + 512);
        poolfinal_kernel<<<GG, 128, 0, stream>>>(bufB, stats + 512, bng[2], bnb[2], batch, linw, linb, (float*)d_out);
    } else {
        gather_kernel<FIN, false><<<ggrid, 256, 0, stream>>>(x, ea, off, srcs, eidx, ew[0], ebv[0], bufA);
        mlp_kernel<FIN><<<mlp_grid, 256, 0, stream>>>(bufA, w1[0], b1[0], w2[0], b2[0], bufB, stats);
        bnrelu_kernel<<<2048, 256, 0, stream>>>(bufB, stats, bng[0], bnb[0], bufA);

        gather_kernel<HDIM, false><<<ggrid, 256, 0, stream>>>(bufA, ea, off, srcs, eidx, ew[1], ebv[1], bufB);
        mlp_kernel<HDIM><<<mlp_grid, 256, 0, stream>>>(bufB, w1[1], b1[1], w2[1], b2[1], bufB, stats + 256);
        bnrelu_kernel<<<2048, 256, 0, stream>>>(bufB, stats + 256, bng[1], bnb[1], bufA);

        gather_kernel<HDIM, false><<<ggrid, 256, 0, stream>>>(bufA, ea, off, srcs, eidx, ew[2], ebv[2], bufB);
        mlp_kernel<HDIM><<<mlp_grid, 256, 0, stream>>>(bufB, w1[2], b1[2], w2[2], b2[2], bufB, stats + 512);
        poolfinal_kernel<<<GG, 128, 0, stream>>>(bufB, stats + 512, bng[2], bnb[2], batch, linw, linb, (float*)d_out);
    }
}

// Round 10
// 592.765 us; speedup vs baseline: 1.4845x; 1.4845x over previous
//
#include <hip/hip_runtime.h>

typedef unsigned int uint;

constexpr int NN   = 50000;
constexpr int EE   = 800000;
constexpr int FIN  = 64;
constexpr int EDIM = 16;
constexpr int HDIM = 128;
constexpr int GG   = 256;
constexpr float BN_EPS_C = 1e-5f;
constexpr int NB   = (NN + 255) / 256;
constexpr int NB1  = (NN + 1 + 255) / 256;

// ===========================================================================
// CSR build
// ===========================================================================
__global__ __launch_bounds__(256) void deg_kernel(
    const int* __restrict__ ei, uint* __restrict__ deg)
{
    const int e = blockIdx.x * 256 + threadIdx.x;
    if (e < EE) atomicAdd(&deg[ei[EE + e]], 1u);
}

__global__ __launch_bounds__(256) void scanA_kernel(
    const uint* __restrict__ deg, uint* __restrict__ bsum)
{
    const int i = blockIdx.x * 256 + threadIdx.x;
    uint v = (i < NN) ? deg[i] : 0u;
#pragma unroll
    for (int o = 32; o > 0; o >>= 1) v += __shfl_xor(v, o, 64);
    __shared__ uint ws[4];
    const int lane = threadIdx.x & 63, wid = threadIdx.x >> 6;
    if (lane == 0) ws[wid] = v;
    __syncthreads();
    if (threadIdx.x == 0) bsum[blockIdx.x] = ws[0] + ws[1] + ws[2] + ws[3];
}

__global__ __launch_bounds__(256) void scanB_kernel(uint* __restrict__ bsum)
{
    const int t = threadIdx.x;
    const int lane = t & 63, wid = t >> 6;
    const uint orig = (t < NB) ? bsum[t] : 0u;
    uint v = orig;
#pragma unroll
    for (int o = 1; o < 64; o <<= 1) {
        uint u = __shfl_up(v, o, 64);
        if (lane >= o) v += u;
    }
    __shared__ uint ws[4];
    if (lane == 63) ws[wid] = v;
    __syncthreads();
    uint add = 0;
    for (int w = 0; w < wid; ++w) add += ws[w];
    v += add;
    if (t < NB) bsum[t] = v - orig;
}

__global__ __launch_bounds__(256) void scanC_kernel(
    const uint* __restrict__ deg, const uint* __restrict__ bbase,
    uint* __restrict__ off, uint* __restrict__ cursor)
{
    const int i = blockIdx.x * 256 + threadIdx.x;
    const int lane = threadIdx.x & 63, wid = threadIdx.x >> 6;
    const uint orig = (i < NN) ? deg[i] : 0u;
    uint v = orig;
#pragma unroll
    for (int o = 1; o < 64; o <<= 1) {
        uint u = __shfl_up(v, o, 64);
        if (lane >= o) v += u;
    }
    __shared__ uint ws[4];
    if (lane == 63) ws[wid] = v;
    __syncthreads();
    uint add = 0;
    for (int w = 0; w < wid; ++w) add += ws[w];
    v += add;
    const uint excl = v - orig + bbase[blockIdx.x];
    if (i < NN) { off[i] = excl; cursor[i] = excl; }
    if (i == NN) off[NN] = EE;
}

template <bool PERM>
__global__ __launch_bounds__(256) void scatter_kernel(
    const int* __restrict__ ei, const float* __restrict__ ea,
    uint* __restrict__ cursor, uint* __restrict__ srcs,
    uint* __restrict__ eidx, float* __restrict__ ea_perm)
{
    const int e = blockIdx.x * 256 + threadIdx.x;
    if (e < EE) {
        const int d = ei[EE + e];
        const uint pos = atomicAdd(&cursor[d], 1u);
        srcs[pos] = (uint)ei[e];
        if (PERM) {
            const float4* s = (const float4*)(ea + (size_t)e * EDIM);
            float4* dst = (float4*)(ea_perm + (size_t)pos * EDIM);
            dst[0] = s[0]; dst[1] = s[1]; dst[2] = s[2]; dst[3] = s[3];
        } else {
            eidx[pos] = (uint)e;
        }
    }
}

// ===========================================================================
// Edge gather (R6 structure): float4/lane, LPN=CIN/4 lanes per node,
// NPB=256/LPN nodes per block-iteration, edge loop unrolled x2.
// Fixes vs R6: (1) launch_bounds(256,3) -> ~170 VGPR budget, (2) weights in
// 16 NAMED float4 registers (macro FMAs) so they stay resident, (3) grid-
// stride outer node loop so the resident weights amortize over many nodes.
// ===========================================================================
#define GFMA16(lin, arr)                                                  \
    lin.x = fmaf(arr[0],  w00.x, lin.x); lin.y = fmaf(arr[0],  w00.y, lin.y); \
    lin.z = fmaf(arr[0],  w00.z, lin.z); lin.w = fmaf(arr[0],  w00.w, lin.w); \
    lin.x = fmaf(arr[1],  w01.x, lin.x); lin.y = fmaf(arr[1],  w01.y, lin.y); \
    lin.z = fmaf(arr[1],  w01.z, lin.z); lin.w = fmaf(arr[1],  w01.w, lin.w); \
    lin.x = fmaf(arr[2],  w02.x, lin.x); lin.y = fmaf(arr[2],  w02.y, lin.y); \
    lin.z = fmaf(arr[2],  w02.z, lin.z); lin.w = fmaf(arr[2],  w02.w, lin.w); \
    lin.x = fmaf(arr[3],  w03.x, lin.x); lin.y = fmaf(arr[3],  w03.y, lin.y); \
    lin.z = fmaf(arr[3],  w03.z, lin.z); lin.w = fmaf(arr[3],  w03.w, lin.w); \
    lin.x = fmaf(arr[4],  w04.x, lin.x); lin.y = fmaf(arr[4],  w04.y, lin.y); \
    lin.z = fmaf(arr[4],  w04.z, lin.z); lin.w = fmaf(arr[4],  w04.w, lin.w); \
    lin.x = fmaf(arr[5],  w05.x, lin.x); lin.y = fmaf(arr[5],  w05.y, lin.y); \
    lin.z = fmaf(arr[5],  w05.z, lin.z); lin.w = fmaf(arr[5],  w05.w, lin.w); \
    lin.x = fmaf(arr[6],  w06.x, lin.x); lin.y = fmaf(arr[6],  w06.y, lin.y); \
    lin.z = fmaf(arr[6],  w06.z, lin.z); lin.w = fmaf(arr[6],  w06.w, lin.w); \
    lin.x = fmaf(arr[7],  w07.x, lin.x); lin.y = fmaf(arr[7],  w07.y, lin.y); \
    lin.z = fmaf(arr[7],  w07.z, lin.z); lin.w = fmaf(arr[7],  w07.w, lin.w); \
    lin.x = fmaf(arr[8],  w08.x, lin.x); lin.y = fmaf(arr[8],  w08.y, lin.y); \
    lin.z = fmaf(arr[8],  w08.z, lin.z); lin.w = fmaf(arr[8],  w08.w, lin.w); \
    lin.x = fmaf(arr[9],  w09.x, lin.x); lin.y = fmaf(arr[9],  w09.y, lin.y); \
    lin.z = fmaf(arr[9],  w09.z, lin.z); lin.w = fmaf(arr[9],  w09.w, lin.w); \
    lin.x = fmaf(arr[10], w10.x, lin.x); lin.y = fmaf(arr[10], w10.y, lin.y); \
    lin.z = fmaf(arr[10], w10.z, lin.z); lin.w = fmaf(arr[10], w10.w, lin.w); \
    lin.x = fmaf(arr[11], w11.x, lin.x); lin.y = fmaf(arr[11], w11.y, lin.y); \
    lin.z = fmaf(arr[11], w11.z, lin.z); lin.w = fmaf(arr[11], w11.w, lin.w); \
    lin.x = fmaf(arr[12], w12.x, lin.x); lin.y = fmaf(arr[12], w12.y, lin.y); \
    lin.z = fmaf(arr[12], w12.z, lin.z); lin.w = fmaf(arr[12], w12.w, lin.w); \
    lin.x = fmaf(arr[13], w13.x, lin.x); lin.y = fmaf(arr[13], w13.y, lin.y); \
    lin.z = fmaf(arr[13], w13.z, lin.z); lin.w = fmaf(arr[13], w13.w, lin.w); \
    lin.x = fmaf(arr[14], w14.x, lin.x); lin.y = fmaf(arr[14], w14.y, lin.y); \
    lin.z = fmaf(arr[14], w14.z, lin.z); lin.w = fmaf(arr[14], w14.w, lin.w); \
    lin.x = fmaf(arr[15], w15.x, lin.x); lin.y = fmaf(arr[15], w15.y, lin.y); \
    lin.z = fmaf(arr[15], w15.z, lin.z); lin.w = fmaf(arr[15], w15.w, lin.w);

template <int CIN, bool PERM>
__global__ __launch_bounds__(256, 3) void gather_kernel(
    const float* __restrict__ X, const float* __restrict__ ea,
    const uint* __restrict__ off, const uint* __restrict__ srcs,
    const uint* __restrict__ eidx, const float* __restrict__ ew,
    const float* __restrict__ eb, float* __restrict__ Hout)
{
    constexpr int LPN = CIN / 4;       // lanes per node
    constexpr int NPB = 256 / LPN;     // nodes per block-iteration
    const int lane = threadIdx.x & (LPN - 1);
    const int nl   = threadIdx.x / LPN;
    const int j4 = lane * 4;

    // weights: 16 named float4 registers, loaded once per block
    const float4 w00 = *(const float4*)&ew[ 0 * CIN + j4];
    const float4 w01 = *(const float4*)&ew[ 1 * CIN + j4];
    const float4 w02 = *(const float4*)&ew[ 2 * CIN + j4];
    const float4 w03 = *(const float4*)&ew[ 3 * CIN + j4];
    const float4 w04 = *(const float4*)&ew[ 4 * CIN + j4];
    const float4 w05 = *(const float4*)&ew[ 5 * CIN + j4];
    const float4 w06 = *(const float4*)&ew[ 6 * CIN + j4];
    const float4 w07 = *(const float4*)&ew[ 7 * CIN + j4];
    const float4 w08 = *(const float4*)&ew[ 8 * CIN + j4];
    const float4 w09 = *(const float4*)&ew[ 9 * CIN + j4];
    const float4 w10 = *(const float4*)&ew[10 * CIN + j4];
    const float4 w11 = *(const float4*)&ew[11 * CIN + j4];
    const float4 w12 = *(const float4*)&ew[12 * CIN + j4];
    const float4 w13 = *(const float4*)&ew[13 * CIN + j4];
    const float4 w14 = *(const float4*)&ew[14 * CIN + j4];
    const float4 w15 = *(const float4*)&ew[15 * CIN + j4];
    const float4 ebv = *(const float4*)&eb[j4];

    for (int n = blockIdx.x * NPB + nl; n < NN; n += gridDim.x * NPB) {
        const uint o0 = off[n], o1 = off[n + 1];
        float4 acc = make_float4(0.f, 0.f, 0.f, 0.f);

        uint idx = o0;
        for (; idx + 2 <= o1; idx += 2) {
            const uint s0 = srcs[idx];
            const uint s1 = srcs[idx + 1];
            const size_t r0 = PERM ? (size_t)idx : (size_t)eidx[idx];
            const size_t r1 = PERM ? (size_t)(idx + 1) : (size_t)eidx[idx + 1];
            const float4* ep0 = (const float4*)(ea + r0 * EDIM);
            const float4* ep1 = (const float4*)(ea + r1 * EDIM);
            float a0[EDIM], a1[EDIM];
            *(float4*)&a0[0]  = ep0[0]; *(float4*)&a0[4]  = ep0[1];
            *(float4*)&a0[8]  = ep0[2]; *(float4*)&a0[12] = ep0[3];
            *(float4*)&a1[0]  = ep1[0]; *(float4*)&a1[4]  = ep1[1];
            *(float4*)&a1[8]  = ep1[2]; *(float4*)&a1[12] = ep1[3];
            const float4 x0 = *(const float4*)&X[(size_t)s0 * CIN + j4];
            const float4 x1 = *(const float4*)&X[(size_t)s1 * CIN + j4];

            float4 l0 = ebv, l1 = ebv;
            GFMA16(l0, a0);
            GFMA16(l1, a1);
            acc.x += fmaxf(x0.x + l0.x, 0.f) + fmaxf(x1.x + l1.x, 0.f);
            acc.y += fmaxf(x0.y + l0.y, 0.f) + fmaxf(x1.y + l1.y, 0.f);
            acc.z += fmaxf(x0.z + l0.z, 0.f) + fmaxf(x1.z + l1.z, 0.f);
            acc.w += fmaxf(x0.w + l0.w, 0.f) + fmaxf(x1.w + l1.w, 0.f);
        }
        if (idx < o1) {  // tail edge
            const uint s0 = srcs[idx];
            const size_t r0 = PERM ? (size_t)idx : (size_t)eidx[idx];
            const float4* ep0 = (const float4*)(ea + r0 * EDIM);
            float a0[EDIM];
            *(float4*)&a0[0]  = ep0[0]; *(float4*)&a0[4]  = ep0[1];
            *(float4*)&a0[8]  = ep0[2]; *(float4*)&a0[12] = ep0[3];
            const float4 x0 = *(const float4*)&X[(size_t)s0 * CIN + j4];
            float4 l0 = ebv;
            GFMA16(l0, a0);
            acc.x += fmaxf(x0.x + l0.x, 0.f);
            acc.y += fmaxf(x0.y + l0.y, 0.f);
            acc.z += fmaxf(x0.z + l0.z, 0.f);
            acc.w += fmaxf(x0.w + l0.w, 0.f);
        }

        const float4 self = *(const float4*)&X[(size_t)n * CIN + j4];
        float4 outv;
        outv.x = acc.x + self.x;
        outv.y = acc.y + self.y;
        outv.z = acc.z + self.z;
        outv.w = acc.w + self.w;
        *(float4*)&Hout[(size_t)n * CIN + j4] = outv;
    }
}

// ===========================================================================
// Fused MLP: Y = relu(H @ W1 + b1) @ W2 + b2 (+ fused BN stats)
// ===========================================================================
template <int K>
__global__ __launch_bounds__(256) void mlp_kernel(
    const float* __restrict__ H,
    const float* __restrict__ w1, const float* __restrict__ b1,
    const float* __restrict__ w2, const float* __restrict__ b2,
    float* __restrict__ Y, float* __restrict__ stats)
{
    __shared__ float Hs[64][K];
    __shared__ float Ts[64][HDIM];

    const int t   = threadIdx.x;
    const int nb0 = blockIdx.x * 64;

    {
        constexpr int V = 64 * K / 4 / 256;
        const float4* src = (const float4*)(H + (size_t)nb0 * K);
        float4* dst = (float4*)(&Hs[0][0]);
#pragma unroll
        for (int i = 0; i < V; ++i) {
            const int i4 = t + 256 * i;
            const int node = nb0 + (i4 * 4) / K;
            float4 v = make_float4(0.f, 0.f, 0.f, 0.f);
            if (node < NN) v = src[i4];
            dst[i4] = v;
        }
    }
    __syncthreads();

    const int tx = t & 31, ty = t >> 5;
    const int jc = tx * 4;
    const int nb = ty * 8;

    float acc[8][4];
#pragma unroll
    for (int i = 0; i < 8; ++i)
#pragma unroll
        for (int c = 0; c < 4; ++c) acc[i][c] = 0.0f;

    for (int k = 0; k < K; k += 2) {
        const float4 wa = *(const float4*)&w1[(k)     * HDIM + jc];
        const float4 wb = *(const float4*)&w1[(k + 1) * HDIM + jc];
#pragma unroll
        for (int i = 0; i < 8; ++i) {
            const float2 h2 = *(const float2*)&Hs[nb + i][k];
            acc[i][0] = fmaf(h2.x, wa.x, acc[i][0]);
            acc[i][1] = fmaf(h2.x, wa.y, acc[i][1]);
            acc[i][2] = fmaf(h2.x, wa.z, acc[i][2]);
            acc[i][3] = fmaf(h2.x, wa.w, acc[i][3]);
            acc[i][0] = fmaf(h2.y, wb.x, acc[i][0]);
            acc[i][1] = fmaf(h2.y, wb.y, acc[i][1]);
            acc[i][2] = fmaf(h2.y, wb.z, acc[i][2]);
            acc[i][3] = fmaf(h2.y, wb.w, acc[i][3]);
        }
    }
    {
        const float4 bb = *(const float4*)&b1[jc];
#pragma unroll
        for (int i = 0; i < 8; ++i) {
            float4 v;
            v.x = fmaxf(acc[i][0] + bb.x, 0.f);
            v.y = fmaxf(acc[i][1] + bb.y, 0.f);
            v.z = fmaxf(acc[i][2] + bb.z, 0.f);
            v.w = fmaxf(acc[i][3] + bb.w, 0.f);
            *(float4*)&Ts[nb + i][jc] = v;
        }
    }
    __syncthreads();

#pragma unroll
    for (int i = 0; i < 8; ++i)
#pragma unroll
        for (int c = 0; c < 4; ++c) acc[i][c] = 0.0f;

    for (int k = 0; k < HDIM; k += 2) {
        const float4 wa = *(const float4*)&w2[(k)     * HDIM + jc];
        const float4 wb = *(const float4*)&w2[(k + 1) * HDIM + jc];
#pragma unroll
        for (int i = 0; i < 8; ++i) {
            const float2 h2 = *(const float2*)&Ts[nb + i][k];
            acc[i][0] = fmaf(h2.x, wa.x, acc[i][0]);
            acc[i][1] = fmaf(h2.x, wa.y, acc[i][1]);
            acc[i][2] = fmaf(h2.x, wa.z, acc[i][2]);
            acc[i][3] = fmaf(h2.x, wa.w, acc[i][3]);
            acc[i][0] = fmaf(h2.y, wb.x, acc[i][0]);
            acc[i][1] = fmaf(h2.y, wb.y, acc[i][1]);
            acc[i][2] = fmaf(h2.y, wb.z, acc[i][2]);
            acc[i][3] = fmaf(h2.y, wb.w, acc[i][3]);
        }
    }

    float sp[4] = {0.f, 0.f, 0.f, 0.f};
    float qp[4] = {0.f, 0.f, 0.f, 0.f};
    {
        const float4 bb = *(const float4*)&b2[jc];
#pragma unroll
        for (int i = 0; i < 8; ++i) {
            const int node = nb0 + nb + i;
            if (node < NN) {
                float4 y;
                y.x = acc[i][0] + bb.x;
                y.y = acc[i][1] + bb.y;
                y.z = acc[i][2] + bb.z;
                y.w = acc[i][3] + bb.w;
                *(float4*)&Y[(size_t)node * HDIM + jc] = y;
                sp[0] += y.x; qp[0] = fmaf(y.x, y.x, qp[0]);
                sp[1] += y.y; qp[1] = fmaf(y.y, y.y, qp[1]);
                sp[2] += y.z; qp[2] = fmaf(y.z, y.z, qp[2]);
                sp[3] += y.w; qp[3] = fmaf(y.w, y.w, qp[3]);
            }
        }
    }
    __syncthreads();
    float* rs = &Ts[0][0];
    float* rq = &Ts[0][0] + 1024;
#pragma unroll
    for (int c = 0; c < 4; ++c) {
        rs[ty * HDIM + jc + c] = sp[c];
        rq[ty * HDIM + jc + c] = qp[c];
    }
    __syncthreads();
    if (t < HDIM) {
        float ss = 0.f, qq = 0.f;
#pragma unroll
        for (int r = 0; r < 8; ++r) {
            ss += rs[r * HDIM + t];
            qq += rq[r * HDIM + t];
        }
        unsafeAtomicAdd(&stats[t], ss);
        unsafeAtomicAdd(&stats[HDIM + t], qq);
    }
}

// ===========================================================================
// BN apply + relu
// ===========================================================================
__global__ __launch_bounds__(256) void bnrelu_kernel(
    const float* __restrict__ Y, const float* __restrict__ stats,
    const float* __restrict__ g, const float* __restrict__ b,
    float* __restrict__ Xo)
{
    constexpr int TOT4 = NN * (HDIM / 4);
    constexpr float inv_n = 1.0f / (float)NN;
    for (int i = blockIdx.x * 256 + threadIdx.x; i < TOT4; i += gridDim.x * 256) {
        const int j4 = i & (HDIM / 4 - 1);
        const float4 y  = ((const float4*)Y)[i];
        const float4 su = ((const float4*)stats)[j4];
        const float4 sq = ((const float4*)(stats + HDIM))[j4];
        const float4 gg = ((const float4*)g)[j4];
        const float4 bb = ((const float4*)b)[j4];
        float4 v;
        {
            float mu = su.x * inv_n, var = sq.x * inv_n - mu * mu;
            v.x = fmaxf((y.x - mu) * (gg.x * rsqrtf(fmaxf(var, 0.f) + BN_EPS_C)) + bb.x, 0.f);
        }
        {
            float mu = su.y * inv_n, var = sq.y * inv_n - mu * mu;
            v.y = fmaxf((y.y - mu) * (gg.y * rsqrtf(fmaxf(var, 0.f) + BN_EPS_C)) + bb.y, 0.f);
        }
        {
            float mu = su.z * inv_n, var = sq.z * inv_n - mu * mu;
            v.z = fmaxf((y.z - mu) * (gg.z * rsqrtf(fmaxf(var, 0.f) + BN_EPS_C)) + bb.z, 0.f);
        }
        {
            float mu = su.w * inv_n, var = sq.w * inv_n - mu * mu;
            v.w = fmaxf((y.w - mu) * (gg.w * rsqrtf(fmaxf(var, 0.f) + BN_EPS_C)) + bb.w, 0.f);
        }
        ((float4*)Xo)[i] = v;
    }
}

// ===========================================================================
// Layer-3 fused: BN+relu + per-graph mean pool + final linear.
// ===========================================================================
__global__ __launch_bounds__(128) void poolfinal_kernel(
    const float* __restrict__ Y, const float* __restrict__ stats,
    const float* __restrict__ g, const float* __restrict__ b,
    const int* __restrict__ batch, const float* __restrict__ lw,
    const float* __restrict__ lb, float* __restrict__ out)
{
    __shared__ float red[2];
    const int gid = blockIdx.x;
    const int j = threadIdx.x;

    auto lower_bound = [&](int key) {
        int lo = 0, hi = NN;
        while (lo < hi) { int m = (lo + hi) >> 1; if (batch[m] < key) lo = m + 1; else hi = m; }
        return lo;
    };
    const int s = lower_bound(gid);
    const int e = lower_bound(gid + 1);

    constexpr float inv_n = 1.0f / (float)NN;
    const float mu  = stats[j] * inv_n;
    const float var = stats[HDIM + j] * inv_n - mu * mu;
    const float sc  = g[j] * rsqrtf(fmaxf(var, 0.f) + BN_EPS_C);
    const float sh  = b[j];

    float acc = 0.0f;
    for (int n = s; n < e; ++n)
        acc += fmaxf((Y[(size_t)n * HDIM + j] - mu) * sc + sh, 0.0f);

    const float cnt = fmaxf((float)(e - s), 1.0f);
    float v = acc / cnt * lw[j];
    for (int o = 32; o > 0; o >>= 1) v += __shfl_down(v, o, 64);
    if ((j & 63) == 0) red[j >> 6] = v;
    __syncthreads();
    if (j == 0) out[gid] = red[0] + red[1] + lb[0];
}

// ===========================================================================
extern "C" void kernel_launch(void* const* d_in, const int* in_sizes, int n_in,
                              void* d_out, int out_size, void* d_ws, size_t ws_size,
                              hipStream_t stream)
{
    const float* x     = (const float*)d_in[0];
    const float* ea    = (const float*)d_in[1];
    const int*   ei    = (const int*)d_in[2];
    const int*   batch = (const int*)d_in[3];

    const float* ew[3]  = {(const float*)d_in[4],  (const float*)d_in[12], (const float*)d_in[20]};
    const float* ebv[3] = {(const float*)d_in[5],  (const float*)d_in[13], (const float*)d_in[21]};
    const float* w1[3]  = {(const float*)d_in[6],  (const float*)d_in[14], (const float*)d_in[22]};
    const float* b1[3]  = {(const float*)d_in[7],  (const float*)d_in[15], (const float*)d_in[23]};
    const float* w2[3]  = {(const float*)d_in[8],  (const float*)d_in[16], (const float*)d_in[24]};
    const float* b2[3]  = {(const float*)d_in[9],  (const float*)d_in[17], (const float*)d_in[25]};
    const float* bng[3] = {(const float*)d_in[10], (const float*)d_in[18], (const float*)d_in[26]};
    const float* bnb[3] = {(const float*)d_in[11], (const float*)d_in[19], (const float*)d_in[27]};
    const float* linw = (const float*)d_in[28];
    const float* linb = (const float*)d_in[29];

    // ---- workspace layout ----
    char* p = (char*)d_ws;
    float* bufA  = (float*)p;  p += (size_t)NN * HDIM * 4;
    float* bufB  = (float*)p;  p += (size_t)NN * HDIM * 4;
    float* stats = (float*)p;  p += 3 * 2 * HDIM * 4;
    uint* off    = (uint*)p;   p += ((NN + 4) & ~3) * 4;
    uint* degcur = (uint*)p;   p += (size_t)NN * 4;
    uint* bsum   = (uint*)p;   p += ((NB + 3) & ~3) * 4;
    uint* srcs   = (uint*)p;   p += (size_t)EE * 4;
    const size_t used_base = (size_t)(p - (char*)d_ws);
    const bool use_perm = ws_size >= used_base + (size_t)EE * EDIM * 4;
    float* ea_perm = (float*)p;
    uint*  eidx    = (uint*)p;

    hipMemsetAsync(degcur, 0, (size_t)NN * 4, stream);
    hipMemsetAsync(stats, 0, 3 * 2 * HDIM * 4, stream);
    deg_kernel<<<(EE + 255) / 256, 256, 0, stream>>>(ei, degcur);
    scanA_kernel<<<NB, 256, 0, stream>>>(degcur, bsum);
    scanB_kernel<<<1, 256, 0, stream>>>(bsum);
    scanC_kernel<<<NB1, 256, 0, stream>>>(degcur, bsum, off, degcur /*cursor*/);
    if (use_perm)
        scatter_kernel<true><<<(EE + 255) / 256, 256, 0, stream>>>(ei, ea, degcur, srcs, eidx, ea_perm);
    else
        scatter_kernel<false><<<(EE + 255) / 256, 256, 0, stream>>>(ei, ea, degcur, srcs, eidx, ea_perm);

    const int mlp_grid = (NN + 63) / 64;
    const int ggrid = 1024;   // grid-stride persistent-ish blocks

    if (use_perm) {
        gather_kernel<FIN, true><<<ggrid, 256, 0, stream>>>(x, ea_perm, off, srcs, eidx, ew[0], ebv[0], bufA);
        mlp_kernel<FIN><<<mlp_grid, 256, 0, stream>>>(bufA, w1[0], b1[0], w2[0], b2[0], bufB, stats);
        bnrelu_kernel<<<2048, 256, 0, stream>>>(bufB, stats, bng[0], bnb[0], bufA);

        gather_kernel<HDIM, true><<<ggrid, 256, 0, stream>>>(bufA, ea_perm, off, srcs, eidx, ew[1], ebv[1], bufB);
        mlp_kernel<HDIM><<<mlp_grid, 256, 0, stream>>>(bufB, w1[1], b1[1], w2[1], b2[1], bufB, stats + 256);
        bnrelu_kernel<<<2048, 256, 0, stream>>>(bufB, stats + 256, bng[1], bnb[1], bufA);

        gather_kernel<HDIM, true><<<ggrid, 256, 0, stream>>>(bufA, ea_perm, off, srcs, eidx, ew[2], ebv[2], bufB);
        mlp_kernel<HDIM><<<mlp_grid, 256, 0, stream>>>(bufB, w1[2], b1[2], w2[2], b2[2], bufB, stats + 512);
        poolfinal_kernel<<<GG, 128, 0, stream>>>(bufB, stats + 512, bng[2], bnb[2], batch, linw, linb, (float*)d_out);
    } else {
        gather_kernel<FIN, false><<<ggrid, 256, 0, stream>>>(x, ea, off, srcs, eidx, ew[0], ebv[0], bufA);
        mlp_kernel<FIN><<<mlp_grid, 256, 0, stream>>>(bufA, w1[0], b1[0], w2[0], b2[0], bufB, stats);
        bnrelu_kernel<<<2048, 256, 0, stream>>>(bufB, stats, bng[0], bnb[0], bufA);

        gather_kernel<HDIM, false><<<ggrid, 256, 0, stream>>>(bufA, ea, off, srcs, eidx, ew[1], ebv[1], bufB);
        mlp_kernel<HDIM><<<mlp_grid, 256, 0, stream>>>(bufB, w1[1], b1[1], w2[1], b2[1], bufB, stats + 256);
        bnrelu_kernel<<<2048, 256, 0, stream>>>(bufB, stats + 256, bng[1], bnb[1], bufA);

        gather_kernel<HDIM, false><<<ggrid, 256, 0, stream>>>(bufA, ea, off, srcs, eidx, ew[2], ebv[2], bufB);
        mlp_kernel<HDIM><<<mlp_grid, 256, 0, stream>>>(bufB, w1[2], b1[2], w2[2], b2[2], bufB, stats + 512);
        poolfinal_kernel<<<GG, 128, 0, stream>>>(bufB, stats + 512, bng[2], bnb[2], batch, linw, linb, (float*)d_out);
    }
}